// Round 1
// baseline (790.067 us; speedup 1.0000x reference)
//
#include <hip/hip_runtime.h>

// LSTM over T=2048 steps, B=2048, IN=5, H=10. Output [T*B, H] fp32.
// Decomposition: 20 lanes per batch element (lane = 2*unit + p).
//   p=0 lane computes gates f (slot a) and i (slot b) for its unit
//   p=1 lane computes gates g (slot a, tanh) and o (slot b) for its unit
// 3 batches per wave (lanes 0..59), 1 wave per block, 683 blocks.
// All cross-lane exchange is intra-wave (DPP shfl_xor + ds_bpermute) -> no
// LDS, no barriers, so the x prefetch pipeline is never drained.
// x is prefetched PF=8 steps ahead in a register ring to cover HBM latency.

#define T_STEPS 2048
#define BATCH   2048
#define NIN     5
#define NH      10
#define PF      8

__device__ __forceinline__ float hw_exp2(float v) { return __builtin_amdgcn_exp2f(v); }
__device__ __forceinline__ float hw_rcp(float v)  { return __builtin_amdgcn_rcpf(v); }

__global__ __launch_bounds__(64) void lstm_fused_kernel(
    const float* __restrict__ x,   const float* __restrict__ hx0,
    const float* __restrict__ cx0, const float* __restrict__ Wih,
    const float* __restrict__ Whh, const float* __restrict__ bih,
    const float* __restrict__ bhh, float* __restrict__ out)
{
    const float LOG2E = 1.4426950408889634f;

    const int lane = threadIdx.x;
    int grp = lane / 20;               // batch group within wave: 0,1,2 (3 = spare)
    const bool act = (grp < 3);
    if (!act) grp = 2;                 // spare lanes duplicate group 2, all writes masked
    int l2 = lane - grp * 20;
    if (l2 > 19) l2 = 19;
    const int j = l2 >> 1;             // hidden unit 0..9
    const int p = l2 & 1;              // gate-pair role

    const int b    = blockIdx.x * 3 + grp;
    const bool bval = act && (b < BATCH);
    const int bl   = (b < BATCH) ? b : (BATCH - 1);

    // torch LSTMCell gate rows: i:[0,10) f:[10,20) g:[20,30) o:[30,40)
    const int row_a = p ? (2 * NH + j) : (NH + j);   // p0: f, p1: g
    const int row_b = p ? (3 * NH + j) : j;          // p0: i, p1: o

    // Weights for this lane's two gates live entirely in registers.
    float wa[NIN + NH], wb[NIN + NH];
#pragma unroll
    for (int k = 0; k < NIN; ++k) {
        wa[k] = Wih[row_a * NIN + k];
        wb[k] = Wih[row_b * NIN + k];
    }
#pragma unroll
    for (int k = 0; k < NH; ++k) {
        wa[NIN + k] = Whh[row_a * NH + k];
        wb[NIN + k] = Whh[row_b * NH + k];
    }
    const float bias_a = bih[row_a] + bhh[row_a];
    const float bias_b = bih[row_b] + bhh[row_b];

    // Uniform nonlinearity: y = A * sigmoid(k*x) + B.
    //   p0 slot a: sigmoid  (k=1, A=1, B=0)
    //   p1 slot a: tanh = 2*sigmoid(2x)-1  (k=2, A=2, B=-1)
    const float ka = p ? (-2.0f * LOG2E) : (-LOG2E);
    const float Aa = p ? 2.0f : 1.0f;
    const float Ba = p ? -1.0f : 0.0f;

    // Every lane holds the full h vector (broadcast via ds_bpermute each step).
    float hv[NH];
#pragma unroll
    for (int k = 0; k < NH; ++k) hv[k] = hx0[bl * NH + k];
    float cst = cx0[bl * NH + j];      // cell state (meaningful in p0 lanes)

    const int srcbase = grp * 20;      // lane holding h of unit 0 for this batch

    // 8-deep x prefetch ring.
    const float* xb = x + (size_t)bl * NIN;
    float xr[PF][NIN];
#pragma unroll
    for (int q = 0; q < PF; ++q) {
#pragma unroll
        for (int k = 0; k < NIN; ++k)
            xr[q][k] = xb[(size_t)q * (BATCH * NIN) + k];
    }

    float* outp = out + (size_t)bl * NH + j;
    const bool do_store = bval && (p == 0);

#pragma unroll 1
    for (int t0 = 0; t0 < T_STEPS; t0 += PF) {
#pragma unroll
        for (int q = 0; q < PF; ++q) {
            const int t = t0 + q;

            // --- gate pre-activations: two dots of length 15, 2 chains each ---
            float a0 = bias_a, a1 = 0.0f, g0 = bias_b, g1 = 0.0f;
            a0 = fmaf(wa[0], xr[q][0], a0);  g0 = fmaf(wb[0], xr[q][0], g0);
            a1 = fmaf(wa[1], xr[q][1], a1);  g1 = fmaf(wb[1], xr[q][1], g1);
            a0 = fmaf(wa[2], xr[q][2], a0);  g0 = fmaf(wb[2], xr[q][2], g0);
            a1 = fmaf(wa[3], xr[q][3], a1);  g1 = fmaf(wb[3], xr[q][3], g1);
            a0 = fmaf(wa[4], xr[q][4], a0);  g0 = fmaf(wb[4], xr[q][4], g0);

            // x(t) consumed -> refill slot with x(t+PF) (clamped at the tail).
            {
                int tn = t + PF;
                if (tn > T_STEPS - 1) tn = T_STEPS - 1;
#pragma unroll
                for (int k = 0; k < NIN; ++k)
                    xr[q][k] = xb[(size_t)tn * (BATCH * NIN) + k];
            }

            a1 = fmaf(wa[5],  hv[0], a1);  g1 = fmaf(wb[5],  hv[0], g1);
            a0 = fmaf(wa[6],  hv[1], a0);  g0 = fmaf(wb[6],  hv[1], g0);
            a1 = fmaf(wa[7],  hv[2], a1);  g1 = fmaf(wb[7],  hv[2], g1);
            a0 = fmaf(wa[8],  hv[3], a0);  g0 = fmaf(wb[8],  hv[3], g0);
            a1 = fmaf(wa[9],  hv[4], a1);  g1 = fmaf(wb[9],  hv[4], g1);
            a0 = fmaf(wa[10], hv[5], a0);  g0 = fmaf(wb[10], hv[5], g0);
            a1 = fmaf(wa[11], hv[6], a1);  g1 = fmaf(wb[11], hv[6], g1);
            a0 = fmaf(wa[12], hv[7], a0);  g0 = fmaf(wb[12], hv[7], g0);
            a1 = fmaf(wa[13], hv[8], a1);  g1 = fmaf(wb[13], hv[8], g1);
            a0 = fmaf(wa[14], hv[9], a0);  g0 = fmaf(wb[14], hv[9], g0);
            const float acc_a = a0 + a1;
            const float acc_b = g0 + g1;

            // --- nonlinearities (uniform across p) ---
            const float sa = hw_rcp(1.0f + hw_exp2(ka * acc_a));
            const float ya = fmaf(Aa, sa, Ba);                       // p0: sig(f), p1: tanh(g)
            const float yb = hw_rcp(1.0f + hw_exp2(-LOG2E * acc_b)); // p0: sig(i), p1: sig(o)

            // --- combine across the p pair (DPP quad_perm) ---
            const float tg = __shfl_xor(ya, 1);  // in p0: tanh(g)
            const float so = __shfl_xor(yb, 1);  // in p0: sig(o)

            // cell update (meaningful in p0 lanes; p1 computes bounded garbage)
            cst = fmaf(ya, cst, yb * tg);        // c = sig(f)*c + sig(i)*tanh(g)
            const float tc = fmaf(2.0f, hw_rcp(1.0f + hw_exp2(-2.0f * LOG2E * cst)), -1.0f);
            const float h = so * tc;             // h = sig(o)*tanh(c)

            if (do_store) outp[(size_t)t * (BATCH * NH)] = h;

            // --- broadcast new h to all 20 lanes of the group (ds_bpermute) ---
#pragma unroll
            for (int k = 0; k < NH; ++k)
                hv[k] = __shfl(h, srcbase + 2 * k);
        }
    }
}

extern "C" void kernel_launch(void* const* d_in, const int* in_sizes, int n_in,
                              void* d_out, int out_size, void* d_ws, size_t ws_size,
                              hipStream_t stream) {
    const float* x   = (const float*)d_in[0];
    const float* hx0 = (const float*)d_in[1];
    const float* cx0 = (const float*)d_in[2];
    const float* Wih = (const float*)d_in[3];
    const float* Whh = (const float*)d_in[4];
    const float* bih = (const float*)d_in[5];
    const float* bhh = (const float*)d_in[6];
    float* out = (float*)d_out;

    const int nblocks = (BATCH + 2) / 3;   // 683 blocks x 64 threads, 3 batches/wave
    lstm_fused_kernel<<<nblocks, 64, 0, stream>>>(x, hx0, cx0, Wih, Whh, bih, bhh, out);
}

// Round 2
// 766.585 us; speedup vs baseline: 1.0306x; 1.0306x over previous
//
#include <hip/hip_runtime.h>

// LSTM, T=2048 steps, B=2048, IN=5, H=10, fp32. Output [T*B, H].
// Latency-bound on the per-step serial chain -> minimize critical path:
//   - 10 lanes per batch (lane = hidden unit j); each lane computes ALL FOUR
//     gates (i,f,g,o) of its unit, so the cell update c,h is lane-local
//     (no cross-lane gate combine -> removes two LDS round-trips per step).
//   - The only cross-lane op is the 10-value h broadcast: one ds_bpermute
//     batch per step, its latency overlapped with the next step's
//     h-independent x-dot and the x prefetch refill.
//   - Gates packed (i,f)/(g,o) as float2 -> v_pk_fma_f32 halves dot issue.
// 6 batches per wave (lanes 0..59), 1 wave/block, 342 blocks.

#define T_STEPS 2048
#define BATCH   2048
#define NIN     5
#define NH      10
#define PF      8
#define GPW     6   // batches (groups of 10 lanes) per wave

typedef float v2f __attribute__((ext_vector_type(2)));

__device__ __forceinline__ float hw_exp2(float v) { return __builtin_amdgcn_exp2f(v); }
__device__ __forceinline__ float hw_rcp(float v)  { return __builtin_amdgcn_rcpf(v); }
__device__ __forceinline__ float bperm_f(int srclane, float v) {
    return __builtin_bit_cast(float,
        __builtin_amdgcn_ds_bpermute(srclane << 2, __builtin_bit_cast(int, v)));
}
__device__ __forceinline__ v2f splat2(float v) { v2f r; r.x = v; r.y = v; return r; }

__global__ __launch_bounds__(64) void lstm_fused_kernel(
    const float* __restrict__ x,   const float* __restrict__ hx0,
    const float* __restrict__ cx0, const float* __restrict__ Wih,
    const float* __restrict__ Whh, const float* __restrict__ bih,
    const float* __restrict__ bhh, float* __restrict__ out)
{
    const float L2E  = 1.4426950408889634f;   // log2(e)
    const float L2E2 = 2.8853900817779268f;   // 2*log2(e)

    const int lane = threadIdx.x;
    int grp = lane / NH;            // 0..6 (lanes 60..63 -> clamp to group 5)
    if (grp > GPW - 1) grp = GPW - 1;
    int j = lane - grp * NH;        // hidden unit 0..9 (spares clamp to 9)
    if (j > NH - 1) j = NH - 1;

    const int b    = blockIdx.x * GPW + grp;
    const bool bval = (lane < GPW * NH) && (b < BATCH);
    const int bl   = (b < BATCH) ? b : (BATCH - 1);

    // torch LSTMCell gate rows: i:[0,10) f:[10,20) g:[20,30) o:[30,40)
    const int ri = j, rf = NH + j, rg = 2 * NH + j, ro = 3 * NH + j;

    // Per-lane weights, packed (i,f) and (g,o).
    v2f wxif[NIN], wxgo[NIN], whif[NH], whgo[NH];
#pragma unroll
    for (int k = 0; k < NIN; ++k) {
        wxif[k].x = Wih[ri * NIN + k];  wxif[k].y = Wih[rf * NIN + k];
        wxgo[k].x = Wih[rg * NIN + k];  wxgo[k].y = Wih[ro * NIN + k];
    }
#pragma unroll
    for (int k = 0; k < NH; ++k) {
        whif[k].x = Whh[ri * NH + k];   whif[k].y = Whh[rf * NH + k];
        whgo[k].x = Whh[rg * NH + k];   whgo[k].y = Whh[ro * NH + k];
    }
    v2f bif, bgo;
    bif.x = bih[ri] + bhh[ri];  bif.y = bih[rf] + bhh[rf];
    bgo.x = bih[rg] + bhh[rg];  bgo.y = bih[ro] + bhh[ro];

    // Full h vector in every lane (refreshed via ds_bpermute each step).
    float hv[NH];
#pragma unroll
    for (int k = 0; k < NH; ++k) hv[k] = hx0[bl * NH + k];
    float cst = cx0[bl * NH + j];   // this lane's unit's cell state (local!)

    const int srcbase = grp * NH;

    // PF-deep x prefetch ring (all 10 lanes of a group load the same 5 floats;
    // L1 broadcast makes this cheap, and it keeps the ring per-lane-register).
    const float* xb = x + (size_t)bl * NIN;
    float xr[PF][NIN];
#pragma unroll
    for (int q = 0; q < PF; ++q)
#pragma unroll
        for (int k = 0; k < NIN; ++k)
            xr[q][k] = xb[(size_t)q * (BATCH * NIN) + k];

    float* outp = out + (size_t)bl * NH + j;

#pragma unroll 1
    for (int t0 = 0; t0 < T_STEPS; t0 += PF) {
#pragma unroll
        for (int q = 0; q < PF; ++q) {
            const int t = t0 + q;

            // ---- x-dot: independent of hv -> issues during broadcast wait ----
            v2f aif0 = bif, ago0 = bgo;
            v2f aif1 = splat2(0.0f), ago1 = splat2(0.0f);
            {
                v2f xx0 = splat2(xr[q][0]);
                v2f xx1 = splat2(xr[q][1]);
                v2f xx2 = splat2(xr[q][2]);
                v2f xx3 = splat2(xr[q][3]);
                v2f xx4 = splat2(xr[q][4]);
                aif0 += xx0 * wxif[0];  ago0 += xx0 * wxgo[0];
                aif1 += xx1 * wxif[1];  ago1 += xx1 * wxgo[1];
                aif0 += xx2 * wxif[2];  ago0 += xx2 * wxgo[2];
                aif1 += xx3 * wxif[3];  ago1 += xx3 * wxgo[3];
                aif0 += xx4 * wxif[4];  ago0 += xx4 * wxgo[4];
            }

            // refill consumed slot with x(t+PF) (clamped at the tail)
            {
                int tn = t + PF;
                if (tn > T_STEPS - 1) tn = T_STEPS - 1;
#pragma unroll
                for (int k = 0; k < NIN; ++k)
                    xr[q][k] = xb[(size_t)tn * (BATCH * NIN) + k];
            }

            // ---- h-dot: first use of hv -> compiler waits lgkmcnt here ----
#pragma unroll
            for (int k = 0; k < NH; k += 2) {
                v2f h0 = splat2(hv[k]);
                v2f h1 = splat2(hv[k + 1]);
                aif0 += h0 * whif[k];      ago0 += h0 * whgo[k];
                aif1 += h1 * whif[k + 1];  ago1 += h1 * whgo[k + 1];
            }
            const v2f aif = aif0 + aif1;
            const v2f ago = ago0 + ago1;

            // ---- lane-local nonlinearities and cell update ----
            const float si = hw_rcp(1.0f + hw_exp2(-L2E  * aif.x));
            const float sf = hw_rcp(1.0f + hw_exp2(-L2E  * aif.y));
            const float tg = fmaf(2.0f, hw_rcp(1.0f + hw_exp2(-L2E2 * ago.x)), -1.0f);
            const float so = hw_rcp(1.0f + hw_exp2(-L2E  * ago.y));

            cst = fmaf(sf, cst, si * tg);                    // c' = sig(f)*c + sig(i)*tanh(g)
            const float tc = fmaf(2.0f, hw_rcp(1.0f + hw_exp2(-L2E2 * cst)), -1.0f);
            const float h  = so * tc;                        // h' = sig(o)*tanh(c')

            if (bval) outp[(size_t)t * (BATCH * NH)] = h;

            // ---- sole cross-lane op: broadcast h[0..9] to the group ----
#pragma unroll
            for (int k = 0; k < NH; ++k)
                hv[k] = bperm_f(srcbase + k, h);
        }
    }
}

extern "C" void kernel_launch(void* const* d_in, const int* in_sizes, int n_in,
                              void* d_out, int out_size, void* d_ws, size_t ws_size,
                              hipStream_t stream) {
    const float* x   = (const float*)d_in[0];
    const float* hx0 = (const float*)d_in[1];
    const float* cx0 = (const float*)d_in[2];
    const float* Wih = (const float*)d_in[3];
    const float* Whh = (const float*)d_in[4];
    const float* bih = (const float*)d_in[5];
    const float* bhh = (const float*)d_in[6];
    float* out = (float*)d_out;

    const int nblocks = (BATCH + GPW - 1) / GPW;   // 342 blocks x 64 threads
    lstm_fused_kernel<<<nblocks, 64, 0, stream>>>(x, hx0, cx0, Wih, Whh, bih, bhh, out);
}